// Round 2
// baseline (75.610 us; speedup 1.0000x reference)
//
#include <hip/hip_runtime.h>

namespace {
constexpr int GH = 48;
constexpr int GW = 64;
constexpr int GHW = GH * GW;       // 3072
constexpr int NT = 256;            // threads per block
constexpr int NPT = GHW / NT;      // 12 points per thread
constexpr int NITER = 30;          // Chebyshev iterations; contraction 0.5/iter
}

// One block per (batch, channel) RHS. Solve (I + Lap_w) x = b by Chebyshev
// semi-iteration with spectral bounds [1, 9] (Gershgorin-safe for weights<1).
__global__ __launch_bounds__(NT)
void gridsmoother_cheb(const float* __restrict__ ae,
                       const float* __restrict__ wxwy,
                       float* __restrict__ out)
{
    const int bc = blockIdx.x;      // batch*16 + channel, 0..63
    const int b  = bc >> 4;
    const int t  = threadIdx.x;

    const float* __restrict__ bvec = ae   + (size_t)bc * GHW;       // ae[b,c,:,:]
    const float* __restrict__ gwx  = wxwy + (size_t)b * 2 * GHW;    // wxwy[b,0]
    const float* __restrict__ gwy  = gwx + GHW;                     // wxwy[b,1]

    __shared__ float s_wx[GHW];
    __shared__ float s_wy[GHW];
    __shared__ float s_d[GHW];

    // Stage weights once (float4-vectorized, coalesced: 768 float4 / 256 thr)
    {
        const float4* __restrict__ wx4 = (const float4*)gwx;
        const float4* __restrict__ wy4 = (const float4*)gwy;
        float4* swx4 = (float4*)s_wx;
        float4* swy4 = (float4*)s_wy;
        #pragma unroll
        for (int k = 0; k < GHW / 4 / NT; ++k) {   // 3 iters
            swx4[t + k * NT] = wx4[t + k * NT];
            swy4[t + k * NT] = wy4[t + k * NT];
        }
    }
    __syncthreads();

    // Per-thread state: x, r, d (search dir, mirrored in LDS), diag, 4 weights
    float x[NPT], r[NPT], d[NPT], dg[NPT];
    float wl[NPT], wr[NPT], wu[NPT], wdn[NPT];

    constexpr float theta  = 5.0f;            // (lmax+lmin)/2, spectrum in [1,9]
    constexpr float delta  = 4.0f;            // (lmax-lmin)/2
    constexpr float sigma1 = theta / delta;   // 1.25

    #pragma unroll
    for (int k = 0; k < NPT; ++k) {
        const int i  = t + k * NT;
        const int yy = i >> 6;                // /64
        const int xx = i & 63;
        // Edge weights incident to node (yy,xx):
        //   horiz edge (y,x-1)-(y,x): wx[y,x-1];  (y,x)-(y,x+1): wx[y,x]
        //   vert  edge (y-1,x)-(y,x): wy[y-1,x];  (y,x)-(y+1,x): wy[y,x]
        wl[k]  = (xx > 0)      ? s_wx[i - 1]  : 0.0f;
        wr[k]  = (xx < GW - 1) ? s_wx[i]      : 0.0f;
        wu[k]  = (yy > 0)      ? s_wy[i - GW] : 0.0f;
        wdn[k] = (yy < GH - 1) ? s_wy[i]      : 0.0f;
        dg[k]  = 1.0f + wl[k] + wr[k] + wu[k] + wdn[k];
        const float bvi = bvec[i];
        x[k] = 0.0f;
        r[k] = bvi;                    // r0 = b - A*0 = b
        d[k] = bvi * (1.0f / theta);   // d0 = r0 / theta
        s_d[i] = d[k];
    }
    __syncthreads();

    float rho = 1.0f / sigma1;   // rho0 = delta/theta = 0.8

    #pragma unroll 1
    for (int it = 0; it < NITER; ++it) {
        // ad = A d  (5-point stencil; boundary weights are 0 so clamped
        // neighbor indices only feed zero-weight products)
        float ad[NPT];
        #pragma unroll
        for (int k = 0; k < NPT; ++k) {
            const int i  = t + k * NT;
            const int yy = i >> 6;
            const int xx = i & 63;
            float acc = dg[k] * d[k];
            acc -= wl[k]  * s_d[(xx > 0)      ? i - 1  : i];
            acc -= wr[k]  * s_d[(xx < GW - 1) ? i + 1  : i];
            acc -= wu[k]  * s_d[(yy > 0)      ? i - GW : i];
            acc -= wdn[k] * s_d[(yy < GH - 1) ? i + GW : i];
            ad[k] = acc;
        }
        const float rho_new = 1.0f / (2.0f * sigma1 - rho);
        const float c1 = rho_new * rho;
        const float c2 = 2.0f * rho_new / delta;
        __syncthreads();           // all reads of old s_d complete
        #pragma unroll
        for (int k = 0; k < NPT; ++k) {
            x[k] += d[k];          // x_{k+1} = x_k + d_k
            r[k] -= ad[k];         // r_{k+1} = r_k - A d_k
            d[k]  = c1 * d[k] + c2 * r[k];
            s_d[t + k * NT] = d[k];
        }
        rho = rho_new;
        __syncthreads();           // new s_d visible to all
    }

    // out[b,c,y,x] = x at (y*64+x) — same layout as ae, coalesced store
    float* __restrict__ obase = out + (size_t)bc * GHW;
    #pragma unroll
    for (int k = 0; k < NPT; ++k) {
        obase[t + k * NT] = x[k];
    }
}

extern "C" void kernel_launch(void* const* d_in, const int* in_sizes, int n_in,
                              void* d_out, int out_size, void* d_ws, size_t ws_size,
                              hipStream_t stream) {
    const float* ae   = (const float*)d_in[0];   // (4,16,48,64) f32
    const float* wxwy = (const float*)d_in[1];   // (4,2,48,64) f32
    float* out = (float*)d_out;                  // (4,16,48,64) f32
    hipLaunchKernelGGL(gridsmoother_cheb, dim3(64), dim3(NT), 0, stream,
                       ae, wxwy, out);
}

// Round 3
// 63.538 us; speedup vs baseline: 1.1900x; 1.1900x over previous
//
#include <hip/hip_runtime.h>

namespace {
constexpr int GH = 48;
constexpr int GW = 64;
constexpr int GHW = GH * GW;       // 3072
constexpr int NT = 1024;           // 16 waves/block -> 4 waves/SIMD on 1 CU
constexpr int NPT = GHW / NT;      // 3 points per thread
constexpr int NITER = 18;          // 2*0.5^18*||x|| ~ 2e-5 << ref fp32 noise 4e-3
}

// One block per (batch, channel) RHS. Solve (I + Lap_w) x = b by Chebyshev
// semi-iteration with spectral bounds [1, 9] (Gershgorin: diag = 1 + sum(w),
// offdiag row sum = sum(w), w in [0,1), <=4 incident edges).
// Double-buffered search direction in LDS -> single barrier per iteration.
__global__ __launch_bounds__(NT)
void gridsmoother_cheb(const float* __restrict__ ae,
                       const float* __restrict__ wxwy,
                       float* __restrict__ out)
{
    const int bc = blockIdx.x;      // batch*16 + channel, 0..63
    const int b  = bc >> 4;
    const int t  = threadIdx.x;

    const float* __restrict__ bvec = ae   + (size_t)bc * GHW;       // ae[b,c]
    const float* __restrict__ gwx  = wxwy + (size_t)b * 2 * GHW;    // wxwy[b,0]
    const float* __restrict__ gwy  = gwx + GHW;                     // wxwy[b,1]

    __shared__ float s_d[2][GHW];   // 24 KB

    float x[NPT], r[NPT], d[NPT], dg[NPT];
    float wl[NPT], wrt[NPT], wu[NPT], wdn[NPT];
    int il[NPT], ir[NPT], iu[NPT], idn[NPT];

    constexpr float theta  = 5.0f;            // (lmax+lmin)/2 for [1,9]
    constexpr float delta  = 4.0f;            // (lmax-lmin)/2
    constexpr float sigma1 = theta / delta;   // 1.25

    #pragma unroll
    for (int k = 0; k < NPT; ++k) {
        const int i  = t + k * NT;
        const int yy = i >> 6;                // /64
        const int xx = i & 63;
        // Clamped neighbor indices; boundary weights are 0 so the clamped
        // reads only feed zero-weight products.
        il[k]  = (xx > 0)      ? i - 1  : i;
        ir[k]  = (xx < GW - 1) ? i + 1  : i;
        iu[k]  = (yy > 0)      ? i - GW : i;
        idn[k] = (yy < GH - 1) ? i + GW : i;
        // Incident edge weights (coalesced global reads, read exactly once)
        wl[k]  = (xx > 0)      ? gwx[i - 1]  : 0.0f;
        wrt[k] = (xx < GW - 1) ? gwx[i]      : 0.0f;
        wu[k]  = (yy > 0)      ? gwy[i - GW] : 0.0f;
        wdn[k] = (yy < GH - 1) ? gwy[i]      : 0.0f;
        dg[k]  = 1.0f + wl[k] + wrt[k] + wu[k] + wdn[k];
        const float bvi = bvec[i];
        x[k] = 0.0f;
        r[k] = bvi;                    // r0 = b - A*0
        d[k] = bvi * (1.0f / theta);   // d0 = r0 / theta
        s_d[0][i] = d[k];
    }
    __syncthreads();

    float rho = 1.0f / sigma1;   // 0.8
    int cur = 0;

    #pragma unroll 1
    for (int it = 0; it < NITER; ++it) {
        const float* __restrict__ sd = s_d[cur];
        float ad[NPT];
        #pragma unroll
        for (int k = 0; k < NPT; ++k) {
            ad[k] = dg[k] * d[k]
                  - wl[k]  * sd[il[k]]  - wrt[k] * sd[ir[k]]
                  - wu[k]  * sd[iu[k]]  - wdn[k] * sd[idn[k]];
        }
        const float rho_new = 1.0f / (2.0f * sigma1 - rho);
        const float c1 = rho_new * rho;
        const float c2 = 2.0f * rho_new / delta;
        float* __restrict__ sn = s_d[cur ^ 1];
        #pragma unroll
        for (int k = 0; k < NPT; ++k) {
            x[k] += d[k];
            r[k] -= ad[k];
            d[k]  = c1 * d[k] + c2 * r[k];
            sn[t + k * NT] = d[k];
        }
        rho = rho_new;
        cur ^= 1;
        // Single barrier: publishes s_d[cur] writes AND fences this iter's
        // reads of the old buffer against next iter's overwrite of it.
        __syncthreads();
    }

    float* __restrict__ obase = out + (size_t)bc * GHW;
    #pragma unroll
    for (int k = 0; k < NPT; ++k) {
        obase[t + k * NT] = x[k];
    }
}

extern "C" void kernel_launch(void* const* d_in, const int* in_sizes, int n_in,
                              void* d_out, int out_size, void* d_ws, size_t ws_size,
                              hipStream_t stream) {
    const float* ae   = (const float*)d_in[0];   // (4,16,48,64) f32
    const float* wxwy = (const float*)d_in[1];   // (4,2,48,64) f32
    float* out = (float*)d_out;                  // (4,16,48,64) f32
    hipLaunchKernelGGL(gridsmoother_cheb, dim3(64), dim3(NT), 0, stream,
                       ae, wxwy, out);
}